// Round 1
// baseline (103.716 us; speedup 1.0000x reference)
//
#include <hip/hip_runtime.h>

#define BATCH 256
#define CH    512
#define HW    196      // 14*14
#define HID   128      // C / RED
#define HW4   49       // HW / 4

// ---------------------------------------------------------------------------
// Kernel A: DCT-weighted spatial pooling.  s[b*CH+c] = dot(x[b,c,:,:], dctw[c,:,:])
// One wave (64 lanes) per (b,c) row; 4 waves per 256-thread block.
// ---------------------------------------------------------------------------
__global__ __launch_bounds__(256) void pool_kernel(const float* __restrict__ x,
                                                   const float* __restrict__ dctw,
                                                   float* __restrict__ s) {
    const int wave = threadIdx.x >> 6;
    const int lane = threadIdx.x & 63;
    const int row  = blockIdx.x * 4 + wave;          // row in [0, BATCH*CH)
    const float* xp = x    + (size_t)row * HW;
    const float* wp = dctw + (size_t)(row & (CH - 1)) * HW;

    float v = xp[lane]       * wp[lane]
            + xp[lane + 64]  * wp[lane + 64]
            + xp[lane + 128] * wp[lane + 128];
    if (lane < 4) v += xp[lane + 192] * wp[lane + 192];

    #pragma unroll
    for (int off = 32; off; off >>= 1) v += __shfl_down(v, off, 64);
    if (lane == 0) s[row] = v;
}

// ---------------------------------------------------------------------------
// Kernel B: excitation MLP + tanh + stable top-k rank mask.  One block per b.
//   hidden = relu(s @ w1.T)   [HID]
//   raw[c] = hidden . w2[c]   (identical summation order per c -> exact ties
//                              preserved, matching jnp stable argsort)
//   mask[c] = 1 if stable-descending-rank(raw[c]) < k[b]
// ---------------------------------------------------------------------------
__global__ __launch_bounds__(512) void mlp_kernel(const float* __restrict__ s,
                                                  const float* __restrict__ w1,
                                                  const float* __restrict__ w2,
                                                  const int*   __restrict__ k_tensor,
                                                  float* __restrict__ bounded,
                                                  float* __restrict__ raw_out,
                                                  float* __restrict__ mask_out) {
    __shared__ float s_lds[CH];
    __shared__ float h_lds[HID];
    __shared__ float r_lds[CH];

    const int b   = blockIdx.x;
    const int tid = threadIdx.x;

    s_lds[tid] = s[b * CH + tid];
    __syncthreads();

    if (tid < HID) {
        float h = 0.0f;
        const float* w1p = w1 + (size_t)tid * CH;
        #pragma unroll 4
        for (int j = 0; j < CH; ++j) h += s_lds[j] * w1p[j];
        h_lds[tid] = fmaxf(h, 0.0f);
    }
    __syncthreads();

    float r = 0.0f;
    const float* w2p = w2 + (size_t)tid * HID;
    #pragma unroll 4
    for (int j = 0; j < HID; ++j) r += h_lds[j] * w2p[j];
    r_lds[tid] = r;
    raw_out[b * CH + tid] = r;
    bounded[b * CH + tid] = tanhf(r);
    __syncthreads();

    // stable descending rank: # strictly greater + # equal with smaller index
    int cnt = 0;
    #pragma unroll 8
    for (int j = 0; j < CH; ++j) {
        const float rj = r_lds[j];
        cnt += (rj > r) || (rj == r && j < tid);
    }
    const int k = k_tensor[b];
    mask_out[b * CH + tid] = (cnt < k) ? 1.0f : 0.0f;
}

// ---------------------------------------------------------------------------
// Kernel C: out = x * mask[row] (float4 grid-stride; 196 % 4 == 0 so each
// float4 lies within a single (b,c) row).
// ---------------------------------------------------------------------------
__global__ __launch_bounds__(256) void gate_kernel(const float* __restrict__ x,
                                                   const float* __restrict__ mask,
                                                   float* __restrict__ out) {
    const int total4 = BATCH * CH * HW4;             // 6,422,528
    const int stride = gridDim.x * blockDim.x;
    for (int i = blockIdx.x * blockDim.x + threadIdx.x; i < total4; i += stride) {
        const int row = i / HW4;                     // constant div -> magic mul
        const float m = mask[row];
        float4 v = ((const float4*)x)[i];
        v.x *= m; v.y *= m; v.z *= m; v.w *= m;
        ((float4*)out)[i] = v;
    }
}

extern "C" void kernel_launch(void* const* d_in, const int* in_sizes, int n_in,
                              void* d_out, int out_size, void* d_ws, size_t ws_size,
                              hipStream_t stream) {
    const float* x    = (const float*)d_in[0];   // [256,512,14,14]
    const float* dctw = (const float*)d_in[1];   // [512,14,14]
    const float* w1   = (const float*)d_in[2];   // [128,512]
    const float* w2   = (const float*)d_in[3];   // [512,128]
    const int*   kt   = (const int*)d_in[4];     // [256]

    float* out     = (float*)d_out;                          // 256*512*196
    float* bounded = out + (size_t)BATCH * CH * HW;          // 256*512
    float* raw     = bounded + BATCH * CH;
    float* mask    = raw + BATCH * CH;
    float* s       = mask + BATCH * CH;

    // A: pooling -> s
    pool_kernel<<<(BATCH * CH) / 4, 256, 0, stream>>>(x, dctw, s);
    // B: MLP + tanh + topk mask
    mlp_kernel<<<BATCH, 512, 0, stream>>>(s, w1, w2, kt, bounded, raw, mask);
    // C: gated output
    gate_kernel<<<4096, 256, 0, stream>>>(x, mask, out);
}

// Round 3
// 88.197 us; speedup vs baseline: 1.1760x; 1.1760x over previous
//
#include <hip/hip_runtime.h>

#define BATCH 256
#define CH    512
#define HW    196      // 14*14
#define HID   128      // C / RED
#define HW4   49       // HW / 4 (float4 count per row)

typedef float f32x4 __attribute__((ext_vector_type(4)));

// ---------------------------------------------------------------------------
// Kernel A: DCT-weighted spatial pooling.  s[row] = dot(x[row,:], dctw[row%CH,:])
// 16-lane group per row, float4 loads (16 lanes x 16B = 256B coalesced segment).
// Each lane: f4 indices gl, gl+16, gl+32 (48 f4s), lane 0 adds the 49th.
// ---------------------------------------------------------------------------
__global__ __launch_bounds__(256) void pool_kernel(const f32x4* __restrict__ x4,
                                                   const f32x4* __restrict__ w4,
                                                   float* __restrict__ s) {
    const int tid = threadIdx.x;
    const int g   = tid >> 4;                 // 16 groups per block
    const int gl  = tid & 15;                 // lane within group
    const int row = blockIdx.x * 16 + g;      // row in [0, BATCH*CH)
    const f32x4* xp = x4 + (size_t)row * HW4;
    const f32x4* wp = w4 + (size_t)(row & (CH - 1)) * HW4;

    float v = 0.0f;
    #pragma unroll
    for (int t = 0; t < 3; ++t) {
        const f32x4 a = xp[gl + 16 * t];
        const f32x4 b = wp[gl + 16 * t];
        v += a.x * b.x + a.y * b.y + a.z * b.z + a.w * b.w;
    }
    if (gl == 0) {
        const f32x4 a = xp[48];
        const f32x4 b = wp[48];
        v += a.x * b.x + a.y * b.y + a.z * b.z + a.w * b.w;
    }

    // reduce across the 16-lane group (xor stays within the group)
    v += __shfl_xor(v, 8, 64);
    v += __shfl_xor(v, 4, 64);
    v += __shfl_xor(v, 2, 64);
    v += __shfl_xor(v, 1, 64);
    if (gl == 0) s[row] = v;
}

// ---------------------------------------------------------------------------
// Kernel B: excitation MLP + tanh + stable top-k rank mask.  One block per b.
// ---------------------------------------------------------------------------
__global__ __launch_bounds__(512) void mlp_kernel(const float* __restrict__ s,
                                                  const float* __restrict__ w1,
                                                  const float* __restrict__ w2,
                                                  const int*   __restrict__ k_tensor,
                                                  float* __restrict__ bounded,
                                                  float* __restrict__ raw_out,
                                                  float* __restrict__ mask_out) {
    __shared__ float s_lds[CH];
    __shared__ float h_lds[HID];
    __shared__ float r_lds[CH];

    const int b   = blockIdx.x;
    const int tid = threadIdx.x;

    s_lds[tid] = s[b * CH + tid];
    __syncthreads();

    if (tid < HID) {
        float h = 0.0f;
        const float* w1p = w1 + (size_t)tid * CH;
        #pragma unroll 4
        for (int j = 0; j < CH; ++j) h += s_lds[j] * w1p[j];
        h_lds[tid] = fmaxf(h, 0.0f);
    }
    __syncthreads();

    float r = 0.0f;
    const float* w2p = w2 + (size_t)tid * HID;
    #pragma unroll 4
    for (int j = 0; j < HID; ++j) r += h_lds[j] * w2p[j];
    r_lds[tid] = r;
    raw_out[b * CH + tid] = r;
    bounded[b * CH + tid] = tanhf(r);
    __syncthreads();

    // stable descending rank: # strictly greater + # equal with smaller index
    int cnt = 0;
    #pragma unroll 8
    for (int j = 0; j < CH; ++j) {
        const float rj = r_lds[j];
        cnt += (rj > r) || (rj == r && j < tid);
    }
    const int k = k_tensor[b];
    mask_out[b * CH + tid] = (cnt < k) ? 1.0f : 0.0f;
}

// ---------------------------------------------------------------------------
// Kernel C: out = x * mask[row].  mask is exactly 0.0 or 1.0:
//   m==1 -> pass x through (bitwise identical to x*1.0)
//   m==0 -> store zeros WITHOUT reading x (saves ~half the read traffic)
// Non-temporal stores keep the 103 MB out-stream from evicting x in L3.
// ---------------------------------------------------------------------------
__global__ __launch_bounds__(256) void gate_kernel(const f32x4* __restrict__ x4,
                                                   const float* __restrict__ mask,
                                                   f32x4* __restrict__ out4) {
    const int total4 = BATCH * CH * HW4;             // 6,422,528
    const int stride = gridDim.x * blockDim.x;
    for (int i = blockIdx.x * blockDim.x + threadIdx.x; i < total4; i += stride) {
        const int row = i / HW4;                     // magic-mul division
        const float m = mask[row];
        f32x4 v;
        if (m != 0.0f) {
            v = x4[i];
        } else {
            v = (f32x4)(0.0f);
        }
        __builtin_nontemporal_store(v, &out4[i]);
    }
}

extern "C" void kernel_launch(void* const* d_in, const int* in_sizes, int n_in,
                              void* d_out, int out_size, void* d_ws, size_t ws_size,
                              hipStream_t stream) {
    const float* x    = (const float*)d_in[0];   // [256,512,14,14]
    const float* dctw = (const float*)d_in[1];   // [512,14,14]
    const float* w1   = (const float*)d_in[2];   // [128,512]
    const float* w2   = (const float*)d_in[3];   // [512,128]
    const int*   kt   = (const int*)d_in[4];     // [256]

    float* out     = (float*)d_out;                          // 256*512*196
    float* bounded = out + (size_t)BATCH * CH * HW;          // 256*512
    float* raw     = bounded + BATCH * CH;
    float* mask    = raw + BATCH * CH;
    float* s       = mask + BATCH * CH;

    // A: pooling -> s   (16 rows per block)
    pool_kernel<<<(BATCH * CH) / 16, 256, 0, stream>>>(
        (const f32x4*)x, (const f32x4*)dctw, s);
    // B: MLP + tanh + topk mask
    mlp_kernel<<<BATCH, 512, 0, stream>>>(s, w1, w2, kt, bounded, raw, mask);
    // C: gated output
    gate_kernel<<<6272, 256, 0, stream>>>((const f32x4*)x, mask, (f32x4*)out);
}